// Round 4
// baseline (367.667 us; speedup 1.0000x reference)
//
#include <hip/hip_runtime.h>
#include <math.h>

#define SEQ   8192
#define NT    64              // one wave per block = one row per wave
#define VPT   128             // values per lane
#define F4PT  32              // float4 per lane

__device__ __forceinline__ float wave_sum(float x) {
    #pragma unroll
    for (int off = 32; off > 0; off >>= 1)
        x += __shfl_xor(x, off, 64);
    return x;
}

// One row per WAVE. No LDS, no __syncthreads: all 20 reduction phases are pure
// in-register 6-shuffle butterflies. Payload = 128 floats/lane. NO min-wave
// launch_bounds hint: rounds 1-2 showed a VGPR cap below natural demand makes
// the allocator shuttle the payload through AGPRs/scratch (12MB scratch in r1),
// which costs more than the occupancy buys. Natural demand ~160-200 VGPR ->
// 2-3 waves/SIMD, fine for an issue-dominated kernel.
__global__ __launch_bounds__(NT) void normalizer_kernel(
        const float* __restrict__ score,
        const int*   __restrict__ mask,
        float*       __restrict__ out)
{
    const int row  = blockIdx.x;
    const int lane = threadIdx.x;

    constexpr double L2E = 1.4426950408889634;               // log2(e)
    constexpr double TH7 = 4.0*0.7*0.7*0.7*0.7*0.7*0.7*0.7;  // theta at t=7 (0.32942 > 0.3)
    const float cu0 = (float)(L2E / 4.0);   // score -> u = score*log2e/theta0
    const float r07 = (float)(1.0 / 0.7);   // theta_t / theta_{t+1}
    const float ce  = (float)(TH7 / 0.3);   // u7 -> w-domain scale (exp2 domain)

    const float4* __restrict__ s4 = (const float4*)(score + (size_t)row * SEQ);
    const int4*   __restrict__ m4 = (const int4*)(mask  + (size_t)row * SEQ);

    // u_t = score * log2e / theta_t, masked -> -inf (exp2(-inf)=0 handles all)
    float u[VPT];
    int cnt = 0;
    #pragma unroll
    for (int j = 0; j < F4PT; ++j) {
        float4 s = s4[j * NT + lane];
        int4   m = m4[j * NT + lane];
        u[4*j+0] = m.x ? s.x * cu0 : -INFINITY;
        u[4*j+1] = m.y ? s.y * cu0 : -INFINITY;
        u[4*j+2] = m.z ? s.z * cu0 : -INFINITY;
        u[4*j+3] = m.w ? s.w * cu0 : -INFINITY;
        cnt += (m.x != 0) + (m.y != 0) + (m.z != 0) + (m.w != 0);
    }

    // ---- fused: mask count + t=0 sum (NA = +inf at t=0: no clamp, no k) ----
    float a0 = 0.f, a1 = 0.f, a2 = 0.f, a3 = 0.f;
    #pragma unroll
    for (int j = 0; j < VPT; j += 4) {
        a0 += __builtin_amdgcn_exp2f(u[j]);
        a1 += __builtin_amdgcn_exp2f(u[j+1]);
        a2 += __builtin_amdgcn_exp2f(u[j+2]);
        a3 += __builtin_amdgcn_exp2f(u[j+3]);
    }
    float s_ = wave_sum((a0 + a1) + (a2 + a3));
    float kf = 0.1f * wave_sum((float)cnt);
    // rescale u to t=1 scale; independent of the reductions -> fills shuffle stalls
    #pragma unroll
    for (int j = 0; j < VPT; ++j) u[j] *= r07;
    const float l2k = __builtin_amdgcn_logf(kf);   // v_log_f32 = log2
    const float rk  = 1.0f / kf;
    // NAcp for iter t+1 = (log2 s_t - log2 k) * theta_t/theta_{t+1}
    float NAcp = (__builtin_amdgcn_logf(s_ + 1e-20f) - l2k) * r07;

    // ---- t = 1..6: identical bodies ----
    for (int t = 1; t < 7; ++t) {
        a0 = 0.f; a1 = 0.f; a2 = 0.f; a3 = 0.f;
        #pragma unroll
        for (int j = 0; j < VPT; j += 4) {
            a0 += __builtin_amdgcn_exp2f(fminf(u[j],   NAcp));
            a1 += __builtin_amdgcn_exp2f(fminf(u[j+1], NAcp));
            a2 += __builtin_amdgcn_exp2f(fminf(u[j+2], NAcp));
            a3 += __builtin_amdgcn_exp2f(fminf(u[j+3], NAcp));
        }
        #pragma unroll
        for (int j = 0; j < VPT; ++j) u[j] *= r07;   // next-iter scale, hides in tail
        float ss = wave_sum((a0 + a1) + (a2 + a3));
        NAcp = (__builtin_amdgcn_logf(ss + 1e-20f) - l2k) * r07;
    }

    // ---- t = 7: last exp step; convert u -> e = exp2(w) under the tail ----
    float eNA;
    {
        a0 = 0.f; a1 = 0.f; a2 = 0.f; a3 = 0.f;
        #pragma unroll
        for (int j = 0; j < VPT; j += 4) {
            a0 += __builtin_amdgcn_exp2f(fminf(u[j],   NAcp));
            a1 += __builtin_amdgcn_exp2f(fminf(u[j+1], NAcp));
            a2 += __builtin_amdgcn_exp2f(fminf(u[j+2], NAcp));
            a3 += __builtin_amdgcn_exp2f(fminf(u[j+3], NAcp));
        }
        #pragma unroll
        for (int j = 0; j < VPT; ++j)
            u[j] = __builtin_amdgcn_exp2f(u[j] * ce);   // e-domain (theta=0.3)
        float ss = wave_sum((a0 + a1) + (a2 + a3));
        // eNA = exp2((log2 s7 - log2 k) * theta7/0.3)
        eNA = __builtin_amdgcn_exp2f((__builtin_amdgcn_logf(ss + 1e-20f) - l2k) * ce);
    }

    // ---- t = 8..19: theta = 0.3; s = sum(min(e, eNA)); eNA' = s/k. No exps. ----
    for (int t = 8; t < 20; ++t) {
        a0 = 0.f; a1 = 0.f; a2 = 0.f; a3 = 0.f;
        #pragma unroll
        for (int j = 0; j < VPT; j += 4) {
            a0 += fminf(u[j],   eNA);
            a1 += fminf(u[j+1], eNA);
            a2 += fminf(u[j+2], eNA);
            a3 += fminf(u[j+3], eNA);
        }
        float ss = wave_sum((a0 + a1) + (a2 + a3));
        eNA = (ss + 1e-20f) * rk;
    }

    // gamma = min(e, eNA) / eNA.  Masked: e = 0 -> 0.
    const float ra = 1.0f / eNA;
    float4* __restrict__ o4 = (float4*)(out + (size_t)row * SEQ);
    #pragma unroll
    for (int j = 0; j < F4PT; ++j) {
        float4 g;
        g.x = fminf(u[4*j+0], eNA) * ra;
        g.y = fminf(u[4*j+1], eNA) * ra;
        g.z = fminf(u[4*j+2], eNA) * ra;
        g.w = fminf(u[4*j+3], eNA) * ra;
        o4[j * NT + lane] = g;
    }
}

extern "C" void kernel_launch(void* const* d_in, const int* in_sizes, int n_in,
                              void* d_out, int out_size, void* d_ws, size_t ws_size,
                              hipStream_t stream) {
    const float* score = (const float*)d_in[0];
    const int*   mask  = (const int*)d_in[1];
    float*       out   = (float*)d_out;
    const int rows = in_sizes[0] / SEQ;          // 4096
    normalizer_kernel<<<rows, NT, 0, stream>>>(score, mask, out);
}

// Round 5
// 326.040 us; speedup vs baseline: 1.1277x; 1.1277x over previous
//
#include <hip/hip_runtime.h>
#include <math.h>

#define SEQ   8192
#define NT    256             // 4 waves per block, ONE row per block
#define VPT   32              // values per lane (fits arch VGPRs: the r1/r2/r4 lesson)
#define F4PT  8               // float4 per lane

__device__ __forceinline__ float wave_sum(float x) {
    #pragma unroll
    for (int off = 32; off > 0; off >>= 1)
        x += __shfl_xor(x, off, 64);
    return x;
}

// One row per 256-thread block (4 waves). Payload = 32 floats/lane + ~30 temps
// fits genuinely in arch VGPRs with NO launch-bounds forcing: r1 (cap->scratch),
// r2 (cap->AGPR shuttle), r4 (128-float payload->AGPR, 1 wave/SIMD) all showed
// that any contortion around the register file costs more than occupancy buys.
// Barriers span only 4 waves; one barrier per phase (double-buffered LDS slots);
// reduction-independent work (u *= 1/0.7 rescale, t=7 e-domain conversion) is
// issued between the LDS write and the barrier to hide in the sync shadow.
__global__ __launch_bounds__(NT) void normalizer_kernel(
        const float* __restrict__ score,
        const int*   __restrict__ mask,
        float*       __restrict__ out)
{
    const int row  = blockIdx.x;
    const int tid  = threadIdx.x;
    const int wid  = tid >> 6;
    const int lane = tid & 63;

    constexpr double L2E = 1.4426950408889634;               // log2(e)
    constexpr double TH7 = 4.0*0.7*0.7*0.7*0.7*0.7*0.7*0.7;  // theta at t=7 (0.32942 > 0.3)
    const float cu0 = (float)(L2E / 4.0);   // score -> u = score*log2e/theta0
    const float r07 = (float)(1.0 / 0.7);   // theta_t / theta_{t+1}
    const float ce  = (float)(TH7 / 0.3);   // u7 -> w-domain scale (exp2 domain)

    const float4* __restrict__ s4 = (const float4*)(score + (size_t)row * SEQ);
    const int4*   __restrict__ m4 = (const int4*)(mask  + (size_t)row * SEQ);

    // u_t = score * log2e / theta_t, masked -> -inf (exp2(-inf)=0 handles all)
    float u[VPT];
    int cnt = 0;
    #pragma unroll
    for (int j = 0; j < F4PT; ++j) {
        float4 s = s4[j * NT + tid];
        int4   m = m4[j * NT + tid];
        u[4*j+0] = m.x ? s.x * cu0 : -INFINITY;
        u[4*j+1] = m.y ? s.y * cu0 : -INFINITY;
        u[4*j+2] = m.z ? s.z * cu0 : -INFINITY;
        u[4*j+3] = m.w ? s.w * cu0 : -INFINITY;
        cnt += (m.x != 0) + (m.y != 0) + (m.z != 0) + (m.w != 0);
    }

    __shared__ float redc[4];
    __shared__ float red[2][4];   // double-buffered: one barrier per phase

    // ---- fused: mask count + t=0 sum (NA = +inf at t=0: no clamp, no k) ----
    float a0 = 0.f, a1 = 0.f, a2 = 0.f, a3 = 0.f;
    #pragma unroll
    for (int j = 0; j < VPT; j += 4) {
        a0 += __builtin_amdgcn_exp2f(u[j]);
        a1 += __builtin_amdgcn_exp2f(u[j+1]);
        a2 += __builtin_amdgcn_exp2f(u[j+2]);
        a3 += __builtin_amdgcn_exp2f(u[j+3]);
    }
    float pc = wave_sum((float)cnt);
    float ps = wave_sum((a0 + a1) + (a2 + a3));
    if (lane == 0) { redc[wid] = pc; red[0][wid] = ps; }
    #pragma unroll
    for (int j = 0; j < VPT; ++j) u[j] *= r07;     // t=1 scale, in sync shadow
    __syncthreads();
    const float kf  = 0.1f * (redc[0] + redc[1] + redc[2] + redc[3]);
    const float l2k = __builtin_amdgcn_logf(kf);   // v_log_f32 = log2
    const float rk  = 1.0f / kf;
    float s_ = red[0][0] + red[0][1] + red[0][2] + red[0][3];
    // NAcp for iter t+1 = (log2 s_t - log2 k) * theta_t/theta_{t+1} = (..)/0.7
    float NAcp = (__builtin_amdgcn_logf(s_ + 1e-20f) - l2k) * r07;

    // ---- t = 1..6: identical bodies ----
    for (int t = 1; t < 7; ++t) {
        a0 = 0.f; a1 = 0.f; a2 = 0.f; a3 = 0.f;
        #pragma unroll
        for (int j = 0; j < VPT; j += 4) {
            a0 += __builtin_amdgcn_exp2f(fminf(u[j],   NAcp));
            a1 += __builtin_amdgcn_exp2f(fminf(u[j+1], NAcp));
            a2 += __builtin_amdgcn_exp2f(fminf(u[j+2], NAcp));
            a3 += __builtin_amdgcn_exp2f(fminf(u[j+3], NAcp));
        }
        float pa = wave_sum((a0 + a1) + (a2 + a3));
        if (lane == 0) red[t & 1][wid] = pa;
        #pragma unroll
        for (int j = 0; j < VPT; ++j) u[j] *= r07; // independent: sync shadow
        __syncthreads();
        s_ = red[t & 1][0] + red[t & 1][1] + red[t & 1][2] + red[t & 1][3];
        NAcp = (__builtin_amdgcn_logf(s_ + 1e-20f) - l2k) * r07;
    }

    // ---- t = 7: last exp step; convert u -> e = exp2(w) in the sync shadow ----
    float eNA;
    {
        a0 = 0.f; a1 = 0.f; a2 = 0.f; a3 = 0.f;
        #pragma unroll
        for (int j = 0; j < VPT; j += 4) {
            a0 += __builtin_amdgcn_exp2f(fminf(u[j],   NAcp));
            a1 += __builtin_amdgcn_exp2f(fminf(u[j+1], NAcp));
            a2 += __builtin_amdgcn_exp2f(fminf(u[j+2], NAcp));
            a3 += __builtin_amdgcn_exp2f(fminf(u[j+3], NAcp));
        }
        float pa = wave_sum((a0 + a1) + (a2 + a3));
        if (lane == 0) red[1][wid] = pa;           // 7 & 1
        #pragma unroll
        for (int j = 0; j < VPT; ++j)
            u[j] = __builtin_amdgcn_exp2f(u[j] * ce);   // e-domain (theta=0.3)
        __syncthreads();
        s_ = red[1][0] + red[1][1] + red[1][2] + red[1][3];
        // eNA = exp2((log2 s7 - log2 k) * theta7/0.3)
        eNA = __builtin_amdgcn_exp2f((__builtin_amdgcn_logf(s_ + 1e-20f) - l2k) * ce);
    }

    // ---- t = 8..19: theta = 0.3; s = sum(min(e, eNA)); eNA' = s/k. No exps. ----
    for (int t = 8; t < 20; ++t) {
        a0 = 0.f; a1 = 0.f; a2 = 0.f; a3 = 0.f;
        #pragma unroll
        for (int j = 0; j < VPT; j += 4) {
            a0 += fminf(u[j],   eNA);
            a1 += fminf(u[j+1], eNA);
            a2 += fminf(u[j+2], eNA);
            a3 += fminf(u[j+3], eNA);
        }
        float pa = wave_sum((a0 + a1) + (a2 + a3));
        if (lane == 0) red[t & 1][wid] = pa;
        __syncthreads();
        s_ = red[t & 1][0] + red[t & 1][1] + red[t & 1][2] + red[t & 1][3];
        eNA = (s_ + 1e-20f) * rk;
    }

    // gamma = min(e, eNA) / eNA.  Masked: e = 0 -> 0.
    const float ra = 1.0f / eNA;
    float4* __restrict__ o4 = (float4*)(out + (size_t)row * SEQ);
    #pragma unroll
    for (int j = 0; j < F4PT; ++j) {
        float4 g;
        g.x = fminf(u[4*j+0], eNA) * ra;
        g.y = fminf(u[4*j+1], eNA) * ra;
        g.z = fminf(u[4*j+2], eNA) * ra;
        g.w = fminf(u[4*j+3], eNA) * ra;
        o4[j * NT + tid] = g;
    }
}

extern "C" void kernel_launch(void* const* d_in, const int* in_sizes, int n_in,
                              void* d_out, int out_size, void* d_ws, size_t ws_size,
                              hipStream_t stream) {
    const float* score = (const float*)d_in[0];
    const int*   mask  = (const int*)d_in[1];
    float*       out   = (float*)d_out;
    const int rows = in_sizes[0] / SEQ;          // 4096
    normalizer_kernel<<<rows, NT, 0, stream>>>(score, mask, out);
}